// Round 5
// baseline (219.766 us; speedup 1.0000x reference)
//
#include <hip/hip_runtime.h>
#include <hip/hip_bf16.h>
#include <math.h>

typedef unsigned short u16;
typedef __attribute__((ext_vector_type(8))) short short8;
typedef __attribute__((ext_vector_type(4))) float floatx4;

constexpr int kN   = 1024;
constexpr int kB   = 256;
constexpr int kE   = 8192;
constexpr int kHD  = 20;
constexpr float kEps = 1e-5f;

static __device__ __forceinline__ float u16_bf16_to_f32(u16 v) {
  return __uint_as_float(((unsigned)v) << 16);
}
static __device__ __forceinline__ void unpack2(unsigned u, float& a, float& b) {
  a = __uint_as_float(u << 16);
  b = __uint_as_float(u & 0xffff0000u);
}
static __device__ __forceinline__ u16 f2bf(float f) {
  __hip_bfloat16 h = __float2bfloat16(f);
  return *reinterpret_cast<u16*>(&h);
}
static __device__ __forceinline__ unsigned pack_bf16(float a, float b) {
  return (unsigned)f2bf(a) | ((unsigned)f2bf(b) << 16);
}

static __device__ __forceinline__ int detect_flag(const unsigned* __restrict__ x) {
  unsigned w = x[threadIdx.x & 63];
  unsigned e = (w >> 7) & 0xFFu;
  bool plaus = (e >= 114u && e <= 136u);
  unsigned long long b = __ballot(plaus);
  return (__popcll(b) >= 32) ? 1 : 0;
}
static __device__ __forceinline__ float ldconv(const void* __restrict__ p, int i, int flag) {
  return flag ? u16_bf16_to_f32(((const u16*)p)[i]) : ((const float*)p)[i];
}

// ---------------- repack W1/W2/Wout into MFMA B-fragment cells (verbatim) ------
static __device__ __forceinline__ void repack_one(const void* __restrict__ src,
                                                  u16* __restrict__ dst,
                                                  int c, int N, int srcbf) {
  int n = c % N;
  int t2 = c / N;
  int q = t2 & 3, kb = t2 >> 2;
  int k0 = kb * 32 + q * 8;
  u16 w[8];
  if (srcbf) {
    const u16* s = (const u16*)src;
#pragma unroll
    for (int j = 0; j < 8; j++) w[j] = s[(size_t)(k0 + j) * N + n];
  } else {
    const float* s = (const float*)src;
#pragma unroll
    for (int j = 0; j < 8; j++) w[j] = f2bf(s[(size_t)(k0 + j) * N + n]);
  }
  uint4 out;
  out.x = (unsigned)w[0] | ((unsigned)w[1] << 16);
  out.y = (unsigned)w[2] | ((unsigned)w[3] << 16);
  out.z = (unsigned)w[4] | ((unsigned)w[5] << 16);
  out.w = (unsigned)w[6] | ((unsigned)w[7] << 16);
  *((uint4*)(dst + (size_t)c * 8)) = out;
}

// ---------------- fused setup (1024 threads/block) ----------------
__global__ __launch_bounds__(1024) void setup_kernel(
    const unsigned* __restrict__ xdet,
    const void* __restrict__ xin,
    const int* __restrict__ ei,
    const void* __restrict__ Wl0, const void* __restrict__ Wr0,
    const void* __restrict__ W1, const void* __restrict__ W2, const void* __restrict__ Wout,
    int* __restrict__ csr_off, int* __restrict__ csr_src,
    float* __restrict__ sums,
    u16* __restrict__ W1p, u16* __restrict__ W2p, u16* __restrict__ Woutp,
    u16* __restrict__ xlb, u16* __restrict__ xrb) {
  int bid = blockIdx.x;
  int t = threadIdx.x;
  if (bid == 0) {
    // ---- verbatim original build_csr_kernel body ----
    __shared__ int cnt[kN];
    __shared__ int tmp[kN];
    __shared__ int cur[kN];
    cnt[t] = 0;
    __syncthreads();
    for (int e = t; e < kE; e += 1024) atomicAdd(&cnt[ei[kE + e]], 1);
    __syncthreads();
    int deg = cnt[t] + 1;  // +1 self loop
    tmp[t] = deg;
    __syncthreads();
    for (int o = 1; o < kN; o <<= 1) {
      int add = (t >= o) ? tmp[t - o] : 0;
      __syncthreads();
      tmp[t] += add;
      __syncthreads();
    }
    int excl = tmp[t] - deg;
    csr_off[t] = excl;
    cur[t] = excl;
    if (t == kN - 1) csr_off[kN] = tmp[t];
    __syncthreads();
    for (int e = t; e < kE; e += 1024) {
      int s = ei[e], d2 = ei[kE + e];
      int pos = atomicAdd(&cur[d2], 1);
      csr_src[pos] = s;
    }
    int pos = atomicAdd(&cur[t], 1);  // self loop
    csr_src[pos] = t;
    if (t < 640) sums[t] = 0.f;  // zero sums0+sums1
  } else if (bid <= 39) {
    int flag = detect_flag(xdet);
    int c = (bid - 1) * 1024 + t;  // 0..39935
    if (c < 34816) repack_one(W1, W1p, c, 256, flag);               // K=1088,N=256
    else if (c < 38912) repack_one(W2, W2p, c - 34816, 128, flag);  // K=256, N=128
    else repack_one(Wout, Woutp, c - 38912, 64, flag);              // K=128, N=64
  } else {
    // lin0: x[b][n][0..7] @ Wl0/Wr0 -> xlb,xrb [n][b][20] bf16
    int flag = detect_flag(xdet);
    __shared__ __align__(16) float wl[8 * kHD], wr[8 * kHD];
    if (t < 8 * kHD) { wl[t] = ldconv(Wl0, t, flag); wr[t] = ldconv(Wr0, t, flag); }
    __syncthreads();
    int n = (bid - 40) * 4 + (t >> 8), b = t & 255;
    float xi[8];
    if (flag) {
      uint4 r = *((const uint4*)((const u16*)xin + ((size_t)b * kN + n) * 8));
      unpack2(r.x, xi[0], xi[1]); unpack2(r.y, xi[2], xi[3]);
      unpack2(r.z, xi[4], xi[5]); unpack2(r.w, xi[6], xi[7]);
    } else {
      const float4* s = (const float4*)((const float*)xin + ((size_t)b * kN + n) * 8);
      float4 v0 = s[0], v1 = s[1];
      xi[0] = v0.x; xi[1] = v0.y; xi[2] = v0.z; xi[3] = v0.w;
      xi[4] = v1.x; xi[5] = v1.y; xi[6] = v1.z; xi[7] = v1.w;
    }
    float ol[kHD], orr[kHD];
#pragma unroll
    for (int j = 0; j < kHD; j++) { ol[j] = 0.f; orr[j] = 0.f; }
#pragma unroll
    for (int i = 0; i < 8; i++) {
      float xv = xi[i];
#pragma unroll
      for (int j4 = 0; j4 < 5; j4++) {
        float4 wv = *((const float4*)&wl[i * kHD + j4 * 4]);
        float4 wu = *((const float4*)&wr[i * kHD + j4 * 4]);
        ol[j4 * 4 + 0] = fmaf(xv, wv.x, ol[j4 * 4 + 0]);
        ol[j4 * 4 + 1] = fmaf(xv, wv.y, ol[j4 * 4 + 1]);
        ol[j4 * 4 + 2] = fmaf(xv, wv.z, ol[j4 * 4 + 2]);
        ol[j4 * 4 + 3] = fmaf(xv, wv.w, ol[j4 * 4 + 3]);
        orr[j4 * 4 + 0] = fmaf(xv, wu.x, orr[j4 * 4 + 0]);
        orr[j4 * 4 + 1] = fmaf(xv, wu.y, orr[j4 * 4 + 1]);
        orr[j4 * 4 + 2] = fmaf(xv, wu.z, orr[j4 * 4 + 2]);
        orr[j4 * 4 + 3] = fmaf(xv, wu.w, orr[j4 * 4 + 3]);
      }
    }
    uint2* pl = (uint2*)(xlb + ((size_t)n * kB + b) * kHD);
    uint2* pr = (uint2*)(xrb + ((size_t)n * kB + b) * kHD);
#pragma unroll
    for (int k = 0; k < 5; k++) {
      pl[k] = make_uint2(pack_bf16(ol[4 * k], ol[4 * k + 1]), pack_bf16(ol[4 * k + 2], ol[4 * k + 3]));
      pr[k] = make_uint2(pack_bf16(orr[4 * k], orr[4 * k + 1]), pack_bf16(orr[4 * k + 2], orr[4 * k + 3]));
    }
  }
}

// ---------------- GATv2 attention: 256 thr/block, 1 node/block, 2-deep prefetch -
__global__ __launch_bounds__(256) void attn_kernel(const u16* __restrict__ xlb,
                                                   const u16* __restrict__ xrb,
                                                   const int* __restrict__ csr_off,
                                                   const int* __restrict__ csr_src,
                                                   const void* __restrict__ attraw,
                                                   const void* __restrict__ braw,
                                                   const unsigned* __restrict__ xdet,
                                                   u16* __restrict__ hout,
                                                   float* __restrict__ sums) {
  __shared__ float satt[kHD], sbias[kHD];
  __shared__ float red[4][2 * kHD];
  int flag = detect_flag(xdet);
  int t = threadIdx.x;
  if (t < kHD) { satt[t] = ldconv(attraw, t, flag); sbias[t] = ldconv(braw, t, flag); }
  __syncthreads();
  int n = blockIdx.x;
  int b = t;

  float ratt[kHD];
#pragma unroll
  for (int f = 0; f < kHD; f++) ratt[f] = satt[f];

  float xrv[kHD];
  {
    const uint2* p = (const uint2*)(xrb + ((size_t)n * kB + b) * kHD);
#pragma unroll
    for (int k = 0; k < 5; k++) {
      uint2 v = p[k];
      unpack2(v.x, xrv[4 * k], xrv[4 * k + 1]);
      unpack2(v.y, xrv[4 * k + 2], xrv[4 * k + 3]);
    }
  }
  float s[4] = {0.f, 0.f, 0.f, 0.f};
  float acc[kHD];
#pragma unroll
  for (int f = 0; f < kHD; f++) acc[f] = 0.f;

  int beg = csr_off[n], end = csr_off[n + 1];
  uint2 r0[5], r1[5];
  {
    const uint2* p = (const uint2*)(xlb + ((size_t)csr_src[beg] * kB + b) * kHD);
#pragma unroll
    for (int k = 0; k < 5; k++) r0[k] = p[k];
  }
  if (beg + 1 < end) {
    const uint2* p = (const uint2*)(xlb + ((size_t)csr_src[beg + 1] * kB + b) * kHD);
#pragma unroll
    for (int k = 0; k < 5; k++) r1[k] = p[k];
  }
  for (int idx = beg; idx < end; idx++) {
    float xs[kHD];
#pragma unroll
    for (int k = 0; k < 5; k++) {
      unpack2(r0[k].x, xs[4 * k], xs[4 * k + 1]);
      unpack2(r0[k].y, xs[4 * k + 2], xs[4 * k + 3]);
    }
#pragma unroll
    for (int k = 0; k < 5; k++) r0[k] = r1[k];
    if (idx + 2 < end) {
      const uint2* p = (const uint2*)(xlb + ((size_t)csr_src[idx + 2] * kB + b) * kHD);
#pragma unroll
      for (int k = 0; k < 5; k++) r1[k] = p[k];
    }
#pragma unroll
    for (int hh = 0; hh < 4; hh++) {
      float e = 0.f;
#pragma unroll
      for (int d = 0; d < 5; d++) {
        int f = hh * 5 + d;
        float v = xs[f] + xrv[f];
        v = fmaxf(v, 0.2f * v);
        e = fmaf(v, ratt[f], e);
      }
      float p = __expf(e);
      s[hh] += p;
#pragma unroll
      for (int d = 0; d < 5; d++) {
        int f = hh * 5 + d;
        acc[f] = fmaf(p, xs[f], acc[f]);
      }
    }
  }
  float hv[kHD];
#pragma unroll
  for (int hh = 0; hh < 4; hh++) {
    float inv = 1.f / s[hh];
#pragma unroll
    for (int d = 0; d < 5; d++) {
      int f = hh * 5 + d;
      hv[f] = fmaf(acc[f], inv, sbias[f]);
    }
  }
  {
    uint2* ph = (uint2*)(hout + ((size_t)n * kB + b) * kHD);
#pragma unroll
    for (int k = 0; k < 5; k++)
      ph[k] = make_uint2(pack_bf16(hv[4 * k], hv[4 * k + 1]), pack_bf16(hv[4 * k + 2], hv[4 * k + 3]));
  }
  int lane = t & 63, wv = t >> 6;
#pragma unroll
  for (int f = 0; f < kHD; f++) {
    float a = hv[f], q = hv[f] * hv[f];
    for (int o = 32; o > 0; o >>= 1) { a += __shfl_down(a, o); q += __shfl_down(q, o); }
    if (lane == 0) { red[wv][f] = a; red[wv][kHD + f] = q; }
  }
  __syncthreads();
  if (t < 2 * kHD)
    atomicAdd(&sums[(blockIdx.x & 7) * 2 * kHD + t],
              red[0][t] + red[1][t] + red[2][t] + red[3][t]);
}

// ---------------- layer 1 linear with inline BN0 fold ----------------
__global__ __launch_bounds__(256) void lin1_kernel(const u16* __restrict__ hb,
                                                   const float* __restrict__ sums0,
                                                   const void* __restrict__ g0,
                                                   const void* __restrict__ be0,
                                                   const void* __restrict__ Wl1,
                                                   const void* __restrict__ Wr1,
                                                   const unsigned* __restrict__ xdet,
                                                   u16* __restrict__ xlb,
                                                   u16* __restrict__ xrb) {
  __shared__ __align__(16) float wl[kHD * kHD], wr[kHD * kHD];
  __shared__ float sbl[kHD], sbr[kHD];
  __shared__ float sa[kHD], sc[kHD], tot[2 * kHD];
  int flag = detect_flag(xdet);
  int t = threadIdx.x;
  if (t < 2 * kHD) {
    float v = 0.f;
    for (int k = 0; k < 8; k++) v += sums0[k * 2 * kHD + t];
    tot[t] = v;
  }
  __syncthreads();
  if (t < kHD) {
    const float inv = 1.0f / (float)(kN * kB);
    float mu = tot[t] * inv;
    float var = tot[kHD + t] * inv - mu * mu;
    float av = ldconv(g0, t, flag) * rsqrtf(var + kEps);
    sa[t] = av;
    sc[t] = ldconv(be0, t, flag) - mu * av;
  }
  __syncthreads();
  for (int idx = t; idx < kHD * kHD; idx += 256) {
    int f = idx / kHD;
    wl[idx] = sa[f] * ldconv(Wl1, idx, flag);
    wr[idx] = sa[f] * ldconv(Wr1, idx, flag);
  }
  if (t < kHD) {
    float sl = 0.f, sr = 0.f;
    for (int f = 0; f < kHD; f++) {
      sl += sc[f] * ldconv(Wl1, f * kHD + t, flag);
      sr += sc[f] * ldconv(Wr1, f * kHD + t, flag);
    }
    sbl[t] = sl;
    sbr[t] = sr;
  }
  __syncthreads();
  int n = blockIdx.x, b = t;
  float hv[kHD];
  {
    const uint2* p = (const uint2*)(hb + ((size_t)n * kB + b) * kHD);
#pragma unroll
    for (int k = 0; k < 5; k++) {
      uint2 v = p[k];
      unpack2(v.x, hv[4 * k], hv[4 * k + 1]);
      unpack2(v.y, hv[4 * k + 2], hv[4 * k + 3]);
    }
  }
  float ol[kHD], orr[kHD];
#pragma unroll
  for (int j = 0; j < kHD; j++) { ol[j] = sbl[j]; orr[j] = sbr[j]; }
#pragma unroll
  for (int f = 0; f < kHD; f++) {
    float xv = hv[f];
#pragma unroll
    for (int j4 = 0; j4 < 5; j4++) {
      float4 wv = *((const float4*)&wl[f * kHD + j4 * 4]);
      float4 wu = *((const float4*)&wr[f * kHD + j4 * 4]);
      ol[j4 * 4 + 0] = fmaf(xv, wv.x, ol[j4 * 4 + 0]);
      ol[j4 * 4 + 1] = fmaf(xv, wv.y, ol[j4 * 4 + 1]);
      ol[j4 * 4 + 2] = fmaf(xv, wv.z, ol[j4 * 4 + 2]);
      ol[j4 * 4 + 3] = fmaf(xv, wv.w, ol[j4 * 4 + 3]);
      orr[j4 * 4 + 0] = fmaf(xv, wu.x, orr[j4 * 4 + 0]);
      orr[j4 * 4 + 1] = fmaf(xv, wu.y, orr[j4 * 4 + 1]);
      orr[j4 * 4 + 2] = fmaf(xv, wu.z, orr[j4 * 4 + 2]);
      orr[j4 * 4 + 3] = fmaf(xv, wu.w, orr[j4 * 4 + 3]);
    }
  }
  uint2* pl = (uint2*)(xlb + ((size_t)n * kB + b) * kHD);
  uint2* pr = (uint2*)(xrb + ((size_t)n * kB + b) * kHD);
#pragma unroll
  for (int k = 0; k < 5; k++) {
    pl[k] = make_uint2(pack_bf16(ol[4 * k], ol[4 * k + 1]), pack_bf16(ol[4 * k + 2], ol[4 * k + 3]));
    pr[k] = make_uint2(pack_bf16(orr[4 * k], orr[4 * k + 1]), pack_bf16(orr[4 * k + 2], orr[4 * k + 3]));
  }
}

// ---------------- pool + BN1 + agg + obs -> FIN[256,1088] bf16 ----------------
__global__ __launch_bounds__(256) void pool_fin_kernel(const u16* __restrict__ hb,
                                                       const float* __restrict__ sums1,
                                                       const void* __restrict__ g1,
                                                       const void* __restrict__ be1,
                                                       const void* __restrict__ Wagg,
                                                       const void* __restrict__ bagg,
                                                       const void* __restrict__ obsraw,
                                                       const unsigned* __restrict__ xdet,
                                                       u16* __restrict__ finb) {
  int flag = detect_flag(xdet);
  int b = blockIdx.x, t = threadIdx.x;
  float acc[kHD];
#pragma unroll
  for (int f = 0; f < kHD; f++) acc[f] = 0.f;
  for (int n = t; n < kN; n += 256) {
    const uint2* p = (const uint2*)(hb + ((size_t)n * kB + b) * kHD);
#pragma unroll
    for (int k = 0; k < 5; k++) {
      uint2 v = p[k];
      float a0, a1, a2, a3;
      unpack2(v.x, a0, a1); unpack2(v.y, a2, a3);
      acc[4 * k] += a0; acc[4 * k + 1] += a1; acc[4 * k + 2] += a2; acc[4 * k + 3] += a3;
    }
  }
  __shared__ float red[4][kHD];
  __shared__ float tot[2 * kHD], pv[kHD];
#pragma unroll
  for (int f = 0; f < kHD; f++) {
    float v = acc[f];
    for (int o = 32; o > 0; o >>= 1) v += __shfl_down(v, o);
    if ((t & 63) == 0) red[t >> 6][f] = v;
  }
  if (t < 2 * kHD) {
    float v = 0.f;
    for (int k = 0; k < 8; k++) v += sums1[k * 2 * kHD + t];
    tot[t] = v;
  }
  __syncthreads();
  if (t < kHD) {
    const float inv = 1.0f / (float)(kN * kB);
    float mu = tot[t] * inv;
    float var = tot[kHD + t] * inv - mu * mu;
    float a1 = ldconv(g1, t, flag) * rsqrtf(var + kEps);
    float c1 = ldconv(be1, t, flag) - mu * a1;
    float pool = (red[0][t] + red[1][t] + red[2][t] + red[3][t]) * (1.0f / kN);
    pv[t] = pool * a1 + c1;
  }
  __syncthreads();
  if (t < 64) {
    float agg = ldconv(bagg, t, flag);
#pragma unroll
    for (int f = 0; f < kHD; f++) agg = fmaf(pv[f], ldconv(Wagg, f * 64 + t, flag), agg);
    finb[(size_t)b * 1088 + t] = f2bf(agg);
  }
  if (t < 128) {
    uint4* dst = (uint4*)(finb + (size_t)b * 1088 + 64 + t * 8);
    if (flag) {
      *dst = *((const uint4*)((const u16*)obsraw + (size_t)b * 1024 + t * 8));
    } else {
      const float4* s = (const float4*)((const float*)obsraw + (size_t)b * 1024 + t * 8);
      float4 r0 = s[0], r1 = s[1];
      uint4 o;
      o.x = pack_bf16(r0.x, r0.y); o.y = pack_bf16(r0.z, r0.w);
      o.z = pack_bf16(r1.x, r1.y); o.w = pack_bf16(r1.z, r1.w);
      *dst = o;
    }
  }
}

// ---------------- MLP layer 1 via MFMA (known-good) ----------------
__global__ __launch_bounds__(256) void mlp1_kernel(const u16* __restrict__ finb,
                                                   const u16* __restrict__ W1p,
                                                   const void* __restrict__ bh1,
                                                   const unsigned* __restrict__ xdet,
                                                   u16* __restrict__ h1b) {
  int flag = detect_flag(xdet);
  int tid = threadIdx.x;
  int wave = tid >> 6, lane = tid & 63;
  int tile = blockIdx.x * 4 + wave;            // 0..255
  int m0 = (tile >> 4) << 4, n0 = (tile & 15) << 4;
  int lo = lane & 15, quad = lane >> 4;
  floatx4 acc = {0.f, 0.f, 0.f, 0.f};
  const u16* ap = finb + (size_t)(m0 + lo) * 1088 + quad * 8;
  const u16* bp = W1p + ((size_t)quad * 256 + n0 + lo) * 8;
  for (int kb = 0; kb < 34; kb++) {
    short8 a = *(const short8*)ap; ap += 32;
    short8 bfr = *(const short8*)bp; bp += 4 * 256 * 8;
    acc = __builtin_amdgcn_mfma_f32_16x16x32_bf16(a, bfr, acc, 0, 0, 0);
  }
  float bias = ldconv(bh1, n0 + lo, flag);
  u16* op = h1b + (size_t)(m0 + quad * 4) * 256 + n0 + lo;
#pragma unroll
  for (int r = 0; r < 4; r++) op[r * 256] = f2bf(tanhf(acc[r] + bias));
}

// ---------------- MLP layers 2+3 via MFMA -> logits (known-good) ----
__global__ __launch_bounds__(256) void mlp23_kernel(const u16* __restrict__ h1b,
                                                    const u16* __restrict__ W2p,
                                                    const u16* __restrict__ Woutp,
                                                    const void* __restrict__ bh2,
                                                    const void* __restrict__ bout,
                                                    const unsigned* __restrict__ xdet,
                                                    void* __restrict__ outv) {
  __shared__ __align__(16) u16 h2s[16][128];
  int flag = detect_flag(xdet);
  int tid = threadIdx.x;
  int wave = tid >> 6, lane = tid & 63;
  int lo = lane & 15, quad = lane >> 4;
  int m0 = blockIdx.x * 16;
#pragma unroll
  for (int i = 0; i < 2; i++) {
    int n0 = (wave * 2 + i) * 16;
    floatx4 acc = {0.f, 0.f, 0.f, 0.f};
    const u16* ap = h1b + (size_t)(m0 + lo) * 256 + quad * 8;
    const u16* bp = W2p + ((size_t)quad * 128 + n0 + lo) * 8;
    for (int kb = 0; kb < 8; kb++) {
      short8 a = *(const short8*)ap; ap += 32;
      short8 bfr = *(const short8*)bp; bp += 4 * 128 * 8;
      acc = __builtin_amdgcn_mfma_f32_16x16x32_bf16(a, bfr, acc, 0, 0, 0);
    }
    float bias = ldconv(bh2, n0 + lo, flag);
#pragma unroll
    for (int r = 0; r < 4; r++) h2s[quad * 4 + r][n0 + lo] = f2bf(tanhf(acc[r] + bias));
  }
  __syncthreads();
  {
    int n0 = wave * 16;
    floatx4 acc = {0.f, 0.f, 0.f, 0.f};
    const u16* bp = Woutp + ((size_t)quad * 64 + n0 + lo) * 8;
    for (int kb = 0; kb < 4; kb++) {
      short8 a = *(const short8*)(&h2s[lo][kb * 32 + quad * 8]);
      short8 bfr = *(const short8*)bp; bp += 4 * 64 * 8;
      acc = __builtin_amdgcn_mfma_f32_16x16x32_bf16(a, bfr, acc, 0, 0, 0);
    }
    float bias = ldconv(bout, n0 + lo, flag);
    if (flag) {
      __hip_bfloat16* o = (__hip_bfloat16*)outv;
#pragma unroll
      for (int r = 0; r < 4; r++)
        o[(size_t)(m0 + quad * 4 + r) * 64 + n0 + lo] = __float2bfloat16(acc[r] + bias);
    } else {
      float* o = (float*)outv;
#pragma unroll
      for (int r = 0; r < 4; r++)
        o[(size_t)(m0 + quad * 4 + r) * 64 + n0 + lo] = acc[r] + bias;
    }
  }
}

// ---------------- launch: 7 dispatches, no memset ----------------
extern "C" void kernel_launch(void* const* d_in, const int* in_sizes, int n_in,
                              void* d_out, int out_size, void* d_ws, size_t ws_size,
                              hipStream_t stream) {
  char* ws = (char*)d_ws;
  float* sums    = (float*)(ws + 0);         // 640 floats: sums0[320]+sums1[320]
  float* sums0   = sums;
  float* sums1   = sums + 320;
  int*   csr_off = (int*)(ws + 2560);        // 4100 B
  int*   csr_src = (int*)(ws + 6912);        // 36864 B -> 43776
  u16*   W1p     = (u16*)(ws + 44032);       // 557056 -> 601088
  u16*   W2p     = (u16*)(ws + 601088);      // 65536  -> 666624
  u16*   Woutp   = (u16*)(ws + 666624);      // 16384  -> 683008
  u16*   h1b     = (u16*)(ws + 683008);      // 131072 -> 814080
  u16*   finb    = (u16*)(ws + 814080);      // 557056 -> 1371136
  u16*   xlb     = (u16*)(ws + 1371136);     // 10485760 -> 11856896
  u16*   xrb     = (u16*)(ws + 11856896);    // 10485760 -> 22342656
  u16*   hb      = (u16*)(ws + 22342656);    // 10485760 -> 32828416

  const unsigned* xdet = (const unsigned*)d_in[0];
  const int* ei = (const int*)d_in[2];

  setup_kernel<<<296, 1024, 0, stream>>>(xdet, d_in[0], ei,
                                         d_in[3], d_in[4],              // Wl0, Wr0
                                         d_in[17], d_in[19], d_in[21],  // W1, W2, Wout
                                         csr_off, csr_src, sums,
                                         W1p, W2p, Woutp, xlb, xrb);
  attn_kernel<<<kN, 256, 0, stream>>>(xlb, xrb, csr_off, csr_src,
                                      d_in[5], d_in[6], xdet, hb, sums0);
  lin1_kernel<<<kN, 256, 0, stream>>>(hb, sums0, d_in[11], d_in[12],
                                      d_in[7], d_in[8], xdet, xlb, xrb);
  attn_kernel<<<kN, 256, 0, stream>>>(xlb, xrb, csr_off, csr_src,
                                      d_in[9], d_in[10], xdet, hb, sums1);
  pool_fin_kernel<<<kB, 256, 0, stream>>>(hb, sums1, d_in[13], d_in[14],
                                          d_in[15], d_in[16], d_in[1], xdet, finb);
  mlp1_kernel<<<64, 256, 0, stream>>>(finb, W1p, d_in[18], xdet, h1b);
  mlp23_kernel<<<16, 256, 0, stream>>>(h1b, W2p, Woutp, d_in[20], d_in[22], xdet, d_out);
}

// Round 6
// 211.471 us; speedup vs baseline: 1.0392x; 1.0392x over previous
//
#include <hip/hip_runtime.h>
#include <hip/hip_bf16.h>
#include <math.h>

typedef unsigned short u16;
typedef __attribute__((ext_vector_type(8))) short short8;
typedef __attribute__((ext_vector_type(4))) float floatx4;

constexpr int kN   = 1024;
constexpr int kB   = 256;
constexpr int kE   = 8192;
constexpr int kHD  = 20;
constexpr float kEps = 1e-5f;

static __device__ __forceinline__ float u16_bf16_to_f32(u16 v) {
  return __uint_as_float(((unsigned)v) << 16);
}
static __device__ __forceinline__ void unpack2(unsigned u, float& a, float& b) {
  a = __uint_as_float(u << 16);
  b = __uint_as_float(u & 0xffff0000u);
}
static __device__ __forceinline__ u16 f2bf(float f) {
  __hip_bfloat16 h = __float2bfloat16(f);
  return *reinterpret_cast<u16*>(&h);
}
static __device__ __forceinline__ unsigned pack_bf16(float a, float b) {
  return (unsigned)f2bf(a) | ((unsigned)f2bf(b) << 16);
}

static __device__ __forceinline__ int detect_flag(const unsigned* __restrict__ x) {
  unsigned w = x[threadIdx.x & 63];
  unsigned e = (w >> 7) & 0xFFu;
  bool plaus = (e >= 114u && e <= 136u);
  unsigned long long b = __ballot(plaus);
  return (__popcll(b) >= 32) ? 1 : 0;
}
static __device__ __forceinline__ float ldconv(const void* __restrict__ p, int i, int flag) {
  return flag ? u16_bf16_to_f32(((const u16*)p)[i]) : ((const float*)p)[i];
}

// ---------------- repack W1/W2/Wout into MFMA B-fragment cells (verbatim) ------
static __device__ __forceinline__ void repack_one(const void* __restrict__ src,
                                                  u16* __restrict__ dst,
                                                  int c, int N, int srcbf) {
  int n = c % N;
  int t2 = c / N;
  int q = t2 & 3, kb = t2 >> 2;
  int k0 = kb * 32 + q * 8;
  u16 w[8];
  if (srcbf) {
    const u16* s = (const u16*)src;
#pragma unroll
    for (int j = 0; j < 8; j++) w[j] = s[(size_t)(k0 + j) * N + n];
  } else {
    const float* s = (const float*)src;
#pragma unroll
    for (int j = 0; j < 8; j++) w[j] = f2bf(s[(size_t)(k0 + j) * N + n]);
  }
  uint4 out;
  out.x = (unsigned)w[0] | ((unsigned)w[1] << 16);
  out.y = (unsigned)w[2] | ((unsigned)w[3] << 16);
  out.z = (unsigned)w[4] | ((unsigned)w[5] << 16);
  out.w = (unsigned)w[6] | ((unsigned)w[7] << 16);
  *((uint4*)(dst + (size_t)c * 8)) = out;
}

// ---------------- fused setup (1024 threads/block) ----------------
__global__ __launch_bounds__(1024) void setup_kernel(
    const unsigned* __restrict__ xdet,
    const void* __restrict__ xin,
    const int* __restrict__ ei,
    const void* __restrict__ Wl0, const void* __restrict__ Wr0,
    const void* __restrict__ W1, const void* __restrict__ W2, const void* __restrict__ Wout,
    int* __restrict__ csr_off, int* __restrict__ csr_src,
    float* __restrict__ sums,
    u16* __restrict__ W1p, u16* __restrict__ W2p, u16* __restrict__ Woutp,
    u16* __restrict__ xlb, u16* __restrict__ xrb) {
  int bid = blockIdx.x;
  int t = threadIdx.x;
  if (bid == 0) {
    // ---- verbatim original build_csr_kernel body ----
    __shared__ int cnt[kN];
    __shared__ int tmp[kN];
    __shared__ int cur[kN];
    cnt[t] = 0;
    __syncthreads();
    for (int e = t; e < kE; e += 1024) atomicAdd(&cnt[ei[kE + e]], 1);
    __syncthreads();
    int deg = cnt[t] + 1;  // +1 self loop
    tmp[t] = deg;
    __syncthreads();
    for (int o = 1; o < kN; o <<= 1) {
      int add = (t >= o) ? tmp[t - o] : 0;
      __syncthreads();
      tmp[t] += add;
      __syncthreads();
    }
    int excl = tmp[t] - deg;
    csr_off[t] = excl;
    cur[t] = excl;
    if (t == kN - 1) csr_off[kN] = tmp[t];
    __syncthreads();
    for (int e = t; e < kE; e += 1024) {
      int s = ei[e], d2 = ei[kE + e];
      int pos = atomicAdd(&cur[d2], 1);
      csr_src[pos] = s;
    }
    int pos = atomicAdd(&cur[t], 1);  // self loop
    csr_src[pos] = t;
    if (t < 640) sums[t] = 0.f;  // zero sums0+sums1
  } else if (bid <= 39) {
    int flag = detect_flag(xdet);
    int c = (bid - 1) * 1024 + t;  // 0..39935
    if (c < 34816) repack_one(W1, W1p, c, 256, flag);               // K=1088,N=256
    else if (c < 38912) repack_one(W2, W2p, c - 34816, 128, flag);  // K=256, N=128
    else repack_one(Wout, Woutp, c - 38912, 64, flag);              // K=128, N=64
  } else {
    // lin0: x[b][n][0..7] @ Wl0/Wr0 -> xlb,xrb [n][b][20] bf16
    int flag = detect_flag(xdet);
    __shared__ __align__(16) float wl[8 * kHD], wr[8 * kHD];
    if (t < 8 * kHD) { wl[t] = ldconv(Wl0, t, flag); wr[t] = ldconv(Wr0, t, flag); }
    __syncthreads();
    int n = (bid - 40) * 4 + (t >> 8), b = t & 255;
    float xi[8];
    if (flag) {
      uint4 r = *((const uint4*)((const u16*)xin + ((size_t)b * kN + n) * 8));
      unpack2(r.x, xi[0], xi[1]); unpack2(r.y, xi[2], xi[3]);
      unpack2(r.z, xi[4], xi[5]); unpack2(r.w, xi[6], xi[7]);
    } else {
      const float4* s = (const float4*)((const float*)xin + ((size_t)b * kN + n) * 8);
      float4 v0 = s[0], v1 = s[1];
      xi[0] = v0.x; xi[1] = v0.y; xi[2] = v0.z; xi[3] = v0.w;
      xi[4] = v1.x; xi[5] = v1.y; xi[6] = v1.z; xi[7] = v1.w;
    }
    float ol[kHD], orr[kHD];
#pragma unroll
    for (int j = 0; j < kHD; j++) { ol[j] = 0.f; orr[j] = 0.f; }
#pragma unroll
    for (int i = 0; i < 8; i++) {
      float xv = xi[i];
#pragma unroll
      for (int j4 = 0; j4 < 5; j4++) {
        float4 wv = *((const float4*)&wl[i * kHD + j4 * 4]);
        float4 wu = *((const float4*)&wr[i * kHD + j4 * 4]);
        ol[j4 * 4 + 0] = fmaf(xv, wv.x, ol[j4 * 4 + 0]);
        ol[j4 * 4 + 1] = fmaf(xv, wv.y, ol[j4 * 4 + 1]);
        ol[j4 * 4 + 2] = fmaf(xv, wv.z, ol[j4 * 4 + 2]);
        ol[j4 * 4 + 3] = fmaf(xv, wv.w, ol[j4 * 4 + 3]);
        orr[j4 * 4 + 0] = fmaf(xv, wu.x, orr[j4 * 4 + 0]);
        orr[j4 * 4 + 1] = fmaf(xv, wu.y, orr[j4 * 4 + 1]);
        orr[j4 * 4 + 2] = fmaf(xv, wu.z, orr[j4 * 4 + 2]);
        orr[j4 * 4 + 3] = fmaf(xv, wu.w, orr[j4 * 4 + 3]);
      }
    }
    uint2* pl = (uint2*)(xlb + ((size_t)n * kB + b) * kHD);
    uint2* pr = (uint2*)(xrb + ((size_t)n * kB + b) * kHD);
#pragma unroll
    for (int k = 0; k < 5; k++) {
      pl[k] = make_uint2(pack_bf16(ol[4 * k], ol[4 * k + 1]), pack_bf16(ol[4 * k + 2], ol[4 * k + 3]));
      pr[k] = make_uint2(pack_bf16(orr[4 * k], orr[4 * k + 1]), pack_bf16(orr[4 * k + 2], orr[4 * k + 3]));
    }
  }
}

// ---------------- GATv2 attention (R3 version: 128 thr, XCD remap) -------------
__global__ __launch_bounds__(128) void attn_kernel(const u16* __restrict__ xlb,
                                                   const u16* __restrict__ xrb,
                                                   const int* __restrict__ csr_off,
                                                   const int* __restrict__ csr_src,
                                                   const void* __restrict__ attraw,
                                                   const void* __restrict__ braw,
                                                   const unsigned* __restrict__ xdet,
                                                   u16* __restrict__ hout,
                                                   float* __restrict__ sums) {
  __shared__ float satt[kHD], sbias[kHD];
  __shared__ float red[2][2 * kHD];
  int flag = detect_flag(xdet);
  int t = threadIdx.x;
  if (t < kHD) { satt[t] = ldconv(attraw, t, flag); sbias[t] = ldconv(braw, t, flag); }
  __syncthreads();
  int bid = blockIdx.x;
  int h = ((bid & 7) >= 4) ? 1 : 0;
  int n = ((bid >> 3) << 2) | (bid & 3);
  int b = (h << 7) | t;

  float ratt[kHD];
#pragma unroll
  for (int f = 0; f < kHD; f++) ratt[f] = satt[f];

  float xrv[kHD];
  {
    const uint2* p = (const uint2*)(xrb + ((size_t)n * kB + b) * kHD);
#pragma unroll
    for (int k = 0; k < 5; k++) {
      uint2 v = p[k];
      unpack2(v.x, xrv[4 * k], xrv[4 * k + 1]);
      unpack2(v.y, xrv[4 * k + 2], xrv[4 * k + 3]);
    }
  }
  float s[4] = {0.f, 0.f, 0.f, 0.f};
  float acc[kHD];
#pragma unroll
  for (int f = 0; f < kHD; f++) acc[f] = 0.f;

  int beg = csr_off[n], end = csr_off[n + 1];
  uint2 r[5];
  {
    const uint2* p = (const uint2*)(xlb + ((size_t)csr_src[beg] * kB + b) * kHD);
#pragma unroll
    for (int k = 0; k < 5; k++) r[k] = p[k];
  }
  for (int idx = beg; idx < end; idx++) {
    float xs[kHD];
#pragma unroll
    for (int k = 0; k < 5; k++) {
      unpack2(r[k].x, xs[4 * k], xs[4 * k + 1]);
      unpack2(r[k].y, xs[4 * k + 2], xs[4 * k + 3]);
    }
    if (idx + 1 < end) {
      const uint2* p = (const uint2*)(xlb + ((size_t)csr_src[idx + 1] * kB + b) * kHD);
#pragma unroll
      for (int k = 0; k < 5; k++) r[k] = p[k];
    }
#pragma unroll
    for (int hh = 0; hh < 4; hh++) {
      float e = 0.f;
#pragma unroll
      for (int d = 0; d < 5; d++) {
        int f = hh * 5 + d;
        float v = xs[f] + xrv[f];
        v = fmaxf(v, 0.2f * v);
        e = fmaf(v, ratt[f], e);
      }
      float p = __expf(e);
      s[hh] += p;
#pragma unroll
      for (int d = 0; d < 5; d++) {
        int f = hh * 5 + d;
        acc[f] = fmaf(p, xs[f], acc[f]);
      }
    }
  }
  float hv[kHD];
#pragma unroll
  for (int hh = 0; hh < 4; hh++) {
    float inv = 1.f / s[hh];
#pragma unroll
    for (int d = 0; d < 5; d++) {
      int f = hh * 5 + d;
      hv[f] = fmaf(acc[f], inv, sbias[f]);
    }
  }
  {
    uint2* ph = (uint2*)(hout + ((size_t)n * kB + b) * kHD);
#pragma unroll
    for (int k = 0; k < 5; k++)
      ph[k] = make_uint2(pack_bf16(hv[4 * k], hv[4 * k + 1]), pack_bf16(hv[4 * k + 2], hv[4 * k + 3]));
  }
  int lane = t & 63, wv = t >> 6;
#pragma unroll
  for (int f = 0; f < kHD; f++) {
    float a = hv[f], q = hv[f] * hv[f];
    for (int o = 32; o > 0; o >>= 1) { a += __shfl_down(a, o); q += __shfl_down(q, o); }
    if (lane == 0) { red[wv][f] = a; red[wv][kHD + f] = q; }
  }
  __syncthreads();
  if (t < 2 * kHD) atomicAdd(&sums[(bid & 7) * 2 * kHD + t], red[0][t] + red[1][t]);
}

// ---------------- fold BN0 once: pack folded W into MFMA B-frags + bias --------
// Bp cell c = q*48 + ncol holds 8 bf16: W'[q*8+jj][ncol], jj=0..7; K padded to 32,
// N padded to 48. cols 0-19 = folded Wl1, 20-39 = folded Wr1, 40-47 = 0.
__global__ __launch_bounds__(256) void fold1_kernel(const float* __restrict__ sums0,
                                                    const void* __restrict__ g0,
                                                    const void* __restrict__ be0,
                                                    const void* __restrict__ Wl1,
                                                    const void* __restrict__ Wr1,
                                                    const unsigned* __restrict__ xdet,
                                                    u16* __restrict__ Bp,
                                                    float* __restrict__ bias48) {
  __shared__ float sa[kHD], sc[kHD], tot[2 * kHD];
  int flag = detect_flag(xdet);
  int t = threadIdx.x;
  if (t < 2 * kHD) {
    float v = 0.f;
    for (int k = 0; k < 8; k++) v += sums0[k * 2 * kHD + t];
    tot[t] = v;
  }
  __syncthreads();
  if (t < kHD) {
    const float inv = 1.0f / (float)(kN * kB);
    float mu = tot[t] * inv;
    float var = tot[kHD + t] * inv - mu * mu;
    float av = ldconv(g0, t, flag) * rsqrtf(var + kEps);
    sa[t] = av;
    sc[t] = ldconv(be0, t, flag) - mu * av;
  }
  __syncthreads();
  if (t < 48) {
    float bv = 0.f;
    if (t < 20) {
      for (int f = 0; f < kHD; f++) bv += sc[f] * ldconv(Wl1, f * kHD + t, flag);
    } else if (t < 40) {
      for (int f = 0; f < kHD; f++) bv += sc[f] * ldconv(Wr1, f * kHD + (t - 20), flag);
    }
    bias48[t] = bv;
  }
  if (t >= 64 && t < 64 + 192) {
    int c = t - 64;               // q*48 + ncol
    int ncol = c % 48, q = c / 48;
    u16 w[8];
#pragma unroll
    for (int jj = 0; jj < 8; jj++) {
      int k = q * 8 + jj;
      float val = 0.f;
      if (k < kHD && ncol < 40) {
        float raw = (ncol < kHD) ? ldconv(Wl1, k * kHD + ncol, flag)
                                 : ldconv(Wr1, k * kHD + (ncol - 20), flag);
        val = sa[k] * raw;
      }
      w[jj] = f2bf(val);
    }
    uint4 out;
    out.x = (unsigned)w[0] | ((unsigned)w[1] << 16);
    out.y = (unsigned)w[2] | ((unsigned)w[3] << 16);
    out.z = (unsigned)w[4] | ((unsigned)w[5] << 16);
    out.w = (unsigned)w[6] | ((unsigned)w[7] << 16);
    *((uint4*)(Bp + (size_t)c * 8)) = out;
  }
}

// ---------------- lin1 as MFMA GEMM: [262144,20(pad32)] @ [32,48] --------------
// No LDS, no barriers. Same fragment conventions as mlp1 (known-good).
__global__ __launch_bounds__(256) void lin1_mfma_kernel(const u16* __restrict__ hb,
                                                        const u16* __restrict__ Bp,
                                                        const float* __restrict__ bias48,
                                                        u16* __restrict__ xlb,
                                                        u16* __restrict__ xrb) {
  int tid = threadIdx.x;
  int wave = tid >> 6, lane = tid & 63;
  int lo = lane & 15, quad = lane >> 4;
  short8 bfr0 = *(const short8*)(Bp + ((size_t)(quad * 48 + 0 + lo)) * 8);
  short8 bfr1 = *(const short8*)(Bp + ((size_t)(quad * 48 + 16 + lo)) * 8);
  short8 bfr2 = *(const short8*)(Bp + ((size_t)(quad * 48 + 32 + lo)) * 8);
  float bc0 = bias48[lo], bc1 = bias48[16 + lo], bc2 = bias48[32 + lo];
  int wtile0 = (blockIdx.x * 4 + wave) * 8;
  for (int it = 0; it < 8; it++) {
    int m0 = (wtile0 + it) << 4;
    const uint2* p = (const uint2*)(hb + (size_t)(m0 + lo) * kHD);
    uint2 w0 = p[0], w1 = p[1], w2 = p[2], w3 = p[3], w4 = p[4];
    // A-frag: k = quad*8..quad*8+7; row features 0-19, zero-pad k>=20
    unsigned aw0 = quad == 0 ? w0.x : quad == 1 ? w2.x : quad == 2 ? w4.x : 0u;
    unsigned aw1 = quad == 0 ? w0.y : quad == 1 ? w2.y : quad == 2 ? w4.y : 0u;
    unsigned aw2 = quad == 0 ? w1.x : quad == 1 ? w3.x : 0u;
    unsigned aw3 = quad == 0 ? w1.y : quad == 1 ? w3.y : 0u;
    union { unsigned u[4]; short8 s; } cvt;
    cvt.u[0] = aw0; cvt.u[1] = aw1; cvt.u[2] = aw2; cvt.u[3] = aw3;
    short8 a = cvt.s;
    floatx4 acc0 = {0.f, 0.f, 0.f, 0.f};
    floatx4 acc1 = {0.f, 0.f, 0.f, 0.f};
    floatx4 acc2 = {0.f, 0.f, 0.f, 0.f};
    acc0 = __builtin_amdgcn_mfma_f32_16x16x32_bf16(a, bfr0, acc0, 0, 0, 0);
    acc1 = __builtin_amdgcn_mfma_f32_16x16x32_bf16(a, bfr1, acc1, 0, 0, 0);
    acc2 = __builtin_amdgcn_mfma_f32_16x16x32_bf16(a, bfr2, acc2, 0, 0, 0);
#pragma unroll
    for (int r = 0; r < 4; r++) {
      size_t row = (size_t)(m0 + quad * 4 + r);
      xlb[row * kHD + lo] = f2bf(acc0[r] + bc0);          // cols 0-15
      int c1 = 16 + lo;                                    // cols 16-31
      float v1 = acc1[r] + bc1;
      if (c1 < kHD) xlb[row * kHD + c1] = f2bf(v1);
      else xrb[row * kHD + (c1 - kHD)] = f2bf(v1);
      int c2 = 12 + lo;                                    // cols 32-47 -> xrb 12-19
      if (c2 < kHD) xrb[row * kHD + c2] = f2bf(acc2[r] + bc2);
    }
  }
}

// ---------------- pool + BN1 + agg + obs -> FIN[256,1088] bf16 ----------------
__global__ __launch_bounds__(256) void pool_fin_kernel(const u16* __restrict__ hb,
                                                       const float* __restrict__ sums1,
                                                       const void* __restrict__ g1,
                                                       const void* __restrict__ be1,
                                                       const void* __restrict__ Wagg,
                                                       const void* __restrict__ bagg,
                                                       const void* __restrict__ obsraw,
                                                       const unsigned* __restrict__ xdet,
                                                       u16* __restrict__ finb) {
  int flag = detect_flag(xdet);
  int b = blockIdx.x, t = threadIdx.x;
  float acc[kHD];
#pragma unroll
  for (int f = 0; f < kHD; f++) acc[f] = 0.f;
  for (int n = t; n < kN; n += 256) {
    const uint2* p = (const uint2*)(hb + ((size_t)n * kB + b) * kHD);
#pragma unroll
    for (int k = 0; k < 5; k++) {
      uint2 v = p[k];
      float a0, a1, a2, a3;
      unpack2(v.x, a0, a1); unpack2(v.y, a2, a3);
      acc[4 * k] += a0; acc[4 * k + 1] += a1; acc[4 * k + 2] += a2; acc[4 * k + 3] += a3;
    }
  }
  __shared__ float red[4][kHD];
  __shared__ float tot[2 * kHD], pv[kHD];
#pragma unroll
  for (int f = 0; f < kHD; f++) {
    float v = acc[f];
    for (int o = 32; o > 0; o >>= 1) v += __shfl_down(v, o);
    if ((t & 63) == 0) red[t >> 6][f] = v;
  }
  if (t < 2 * kHD) {
    float v = 0.f;
    for (int k = 0; k < 8; k++) v += sums1[k * 2 * kHD + t];
    tot[t] = v;
  }
  __syncthreads();
  if (t < kHD) {
    const float inv = 1.0f / (float)(kN * kB);
    float mu = tot[t] * inv;
    float var = tot[kHD + t] * inv - mu * mu;
    float a1 = ldconv(g1, t, flag) * rsqrtf(var + kEps);
    float c1 = ldconv(be1, t, flag) - mu * a1;
    float pool = (red[0][t] + red[1][t] + red[2][t] + red[3][t]) * (1.0f / kN);
    pv[t] = pool * a1 + c1;
  }
  __syncthreads();
  if (t < 64) {
    float agg = ldconv(bagg, t, flag);
#pragma unroll
    for (int f = 0; f < kHD; f++) agg = fmaf(pv[f], ldconv(Wagg, f * 64 + t, flag), agg);
    finb[(size_t)b * 1088 + t] = f2bf(agg);
  }
  if (t < 128) {
    uint4* dst = (uint4*)(finb + (size_t)b * 1088 + 64 + t * 8);
    if (flag) {
      *dst = *((const uint4*)((const u16*)obsraw + (size_t)b * 1024 + t * 8));
    } else {
      const float4* s = (const float4*)((const float*)obsraw + (size_t)b * 1024 + t * 8);
      float4 r0 = s[0], r1 = s[1];
      uint4 o;
      o.x = pack_bf16(r0.x, r0.y); o.y = pack_bf16(r0.z, r0.w);
      o.z = pack_bf16(r1.x, r1.y); o.w = pack_bf16(r1.z, r1.w);
      *dst = o;
    }
  }
}

// ---------------- MLP layer 1 via MFMA (known-good) ----------------
__global__ __launch_bounds__(256) void mlp1_kernel(const u16* __restrict__ finb,
                                                   const u16* __restrict__ W1p,
                                                   const void* __restrict__ bh1,
                                                   const unsigned* __restrict__ xdet,
                                                   u16* __restrict__ h1b) {
  int flag = detect_flag(xdet);
  int tid = threadIdx.x;
  int wave = tid >> 6, lane = tid & 63;
  int tile = blockIdx.x * 4 + wave;            // 0..255
  int m0 = (tile >> 4) << 4, n0 = (tile & 15) << 4;
  int lo = lane & 15, quad = lane >> 4;
  floatx4 acc = {0.f, 0.f, 0.f, 0.f};
  const u16* ap = finb + (size_t)(m0 + lo) * 1088 + quad * 8;
  const u16* bp = W1p + ((size_t)quad * 256 + n0 + lo) * 8;
  for (int kb = 0; kb < 34; kb++) {
    short8 a = *(const short8*)ap; ap += 32;
    short8 bfr = *(const short8*)bp; bp += 4 * 256 * 8;
    acc = __builtin_amdgcn_mfma_f32_16x16x32_bf16(a, bfr, acc, 0, 0, 0);
  }
  float bias = ldconv(bh1, n0 + lo, flag);
  u16* op = h1b + (size_t)(m0 + quad * 4) * 256 + n0 + lo;
#pragma unroll
  for (int r = 0; r < 4; r++) op[r * 256] = f2bf(tanhf(acc[r] + bias));
}

// ---------------- MLP layers 2+3 via MFMA -> logits (known-good) ----
__global__ __launch_bounds__(256) void mlp23_kernel(const u16* __restrict__ h1b,
                                                    const u16* __restrict__ W2p,
                                                    const u16* __restrict__ Woutp,
                                                    const void* __restrict__ bh2,
                                                    const void* __restrict__ bout,
                                                    const unsigned* __restrict__ xdet,
                                                    void* __restrict__ outv) {
  __shared__ __align__(16) u16 h2s[16][128];
  int flag = detect_flag(xdet);
  int tid = threadIdx.x;
  int wave = tid >> 6, lane = tid & 63;
  int lo = lane & 15, quad = lane >> 4;
  int m0 = blockIdx.x * 16;
#pragma unroll
  for (int i = 0; i < 2; i++) {
    int n0 = (wave * 2 + i) * 16;
    floatx4 acc = {0.f, 0.f, 0.f, 0.f};
    const u16* ap = h1b + (size_t)(m0 + lo) * 256 + quad * 8;
    const u16* bp = W2p + ((size_t)quad * 128 + n0 + lo) * 8;
    for (int kb = 0; kb < 8; kb++) {
      short8 a = *(const short8*)ap; ap += 32;
      short8 bfr = *(const short8*)bp; bp += 4 * 128 * 8;
      acc = __builtin_amdgcn_mfma_f32_16x16x32_bf16(a, bfr, acc, 0, 0, 0);
    }
    float bias = ldconv(bh2, n0 + lo, flag);
#pragma unroll
    for (int r = 0; r < 4; r++) h2s[quad * 4 + r][n0 + lo] = f2bf(tanhf(acc[r] + bias));
  }
  __syncthreads();
  {
    int n0 = wave * 16;
    floatx4 acc = {0.f, 0.f, 0.f, 0.f};
    const u16* bp = Woutp + ((size_t)quad * 64 + n0 + lo) * 8;
    for (int kb = 0; kb < 4; kb++) {
      short8 a = *(const short8*)(&h2s[lo][kb * 32 + quad * 8]);
      short8 bfr = *(const short8*)bp; bp += 4 * 64 * 8;
      acc = __builtin_amdgcn_mfma_f32_16x16x32_bf16(a, bfr, acc, 0, 0, 0);
    }
    float bias = ldconv(bout, n0 + lo, flag);
    if (flag) {
      __hip_bfloat16* o = (__hip_bfloat16*)outv;
#pragma unroll
      for (int r = 0; r < 4; r++)
        o[(size_t)(m0 + quad * 4 + r) * 64 + n0 + lo] = __float2bfloat16(acc[r] + bias);
    } else {
      float* o = (float*)outv;
#pragma unroll
      for (int r = 0; r < 4; r++)
        o[(size_t)(m0 + quad * 4 + r) * 64 + n0 + lo] = acc[r] + bias;
    }
  }
}

// ---------------- launch: 8 dispatches, no memset ----------------
extern "C" void kernel_launch(void* const* d_in, const int* in_sizes, int n_in,
                              void* d_out, int out_size, void* d_ws, size_t ws_size,
                              hipStream_t stream) {
  char* ws = (char*)d_ws;
  float* sums    = (float*)(ws + 0);         // 640 floats: sums0[320]+sums1[320]
  float* sums0   = sums;
  float* sums1   = sums + 320;
  int*   csr_off = (int*)(ws + 2560);        // 4100 B
  int*   csr_src = (int*)(ws + 6912);        // 36864 B -> 43776
  u16*   W1p     = (u16*)(ws + 44032);       // 557056 -> 601088
  u16*   W2p     = (u16*)(ws + 601088);      // 65536  -> 666624
  u16*   Woutp   = (u16*)(ws + 666624);      // 16384  -> 683008
  u16*   h1b     = (u16*)(ws + 683008);      // 131072 -> 814080
  u16*   finb    = (u16*)(ws + 814080);      // 557056 -> 1371136
  u16*   Bp      = (u16*)(ws + 1371136);     // 3072   -> 1374208
  float* bias48  = (float*)(ws + 1374208);   // 192    -> 1374400
  u16*   xlb     = (u16*)(ws + 1374720);     // 10485760 -> 11860480
  u16*   xrb     = (u16*)(ws + 11860480);    // 10485760 -> 22346240
  u16*   hb      = (u16*)(ws + 22346240);    // 10485760 -> 32832000

  const unsigned* xdet = (const unsigned*)d_in[0];
  const int* ei = (const int*)d_in[2];

  setup_kernel<<<296, 1024, 0, stream>>>(xdet, d_in[0], ei,
                                         d_in[3], d_in[4],              // Wl0, Wr0
                                         d_in[17], d_in[19], d_in[21],  // W1, W2, Wout
                                         csr_off, csr_src, sums,
                                         W1p, W2p, Woutp, xlb, xrb);
  attn_kernel<<<2 * kN, 128, 0, stream>>>(xlb, xrb, csr_off, csr_src,
                                          d_in[5], d_in[6], xdet, hb, sums0);
  fold1_kernel<<<1, 256, 0, stream>>>(sums0, d_in[11], d_in[12],
                                      d_in[7], d_in[8], xdet, Bp, bias48);
  lin1_mfma_kernel<<<512, 256, 0, stream>>>(hb, Bp, bias48, xlb, xrb);
  attn_kernel<<<2 * kN, 128, 0, stream>>>(xlb, xrb, csr_off, csr_src,
                                          d_in[9], d_in[10], xdet, hb, sums1);
  pool_fin_kernel<<<kB, 256, 0, stream>>>(hb, sums1, d_in[13], d_in[14],
                                          d_in[15], d_in[16], d_in[1], xdet, finb);
  mlp1_kernel<<<64, 256, 0, stream>>>(finb, W1p, d_in[18], xdet, h1b);
  mlp23_kernel<<<16, 256, 0, stream>>>(h1b, W2p, Woutp, d_in[20], d_in[22], xdet, d_out);
}

// Round 7
// 210.372 us; speedup vs baseline: 1.0447x; 1.0052x over previous
//
#include <hip/hip_runtime.h>
#include <hip/hip_bf16.h>
#include <math.h>

typedef unsigned short u16;
typedef __attribute__((ext_vector_type(8))) short short8;
typedef __attribute__((ext_vector_type(4))) float floatx4;

constexpr int kN   = 1024;
constexpr int kB   = 256;
constexpr int kE   = 8192;
constexpr int kHD  = 20;
constexpr float kEps = 1e-5f;

static __device__ __forceinline__ float u16_bf16_to_f32(u16 v) {
  return __uint_as_float(((unsigned)v) << 16);
}
static __device__ __forceinline__ void unpack2(unsigned u, float& a, float& b) {
  a = __uint_as_float(u << 16);
  b = __uint_as_float(u & 0xffff0000u);
}
static __device__ __forceinline__ u16 f2bf(float f) {
  __hip_bfloat16 h = __float2bfloat16(f);
  return *reinterpret_cast<u16*>(&h);
}
static __device__ __forceinline__ unsigned pack_bf16(float a, float b) {
  return (unsigned)f2bf(a) | ((unsigned)f2bf(b) << 16);
}

static __device__ __forceinline__ int detect_flag(const unsigned* __restrict__ x) {
  unsigned w = x[threadIdx.x & 63];
  unsigned e = (w >> 7) & 0xFFu;
  bool plaus = (e >= 114u && e <= 136u);
  unsigned long long b = __ballot(plaus);
  return (__popcll(b) >= 32) ? 1 : 0;
}
static __device__ __forceinline__ float ldconv(const void* __restrict__ p, int i, int flag) {
  return flag ? u16_bf16_to_f32(((const u16*)p)[i]) : ((const float*)p)[i];
}

// ---------------- repack W1/W2/Wout into MFMA B-fragment cells (verbatim) ------
static __device__ __forceinline__ void repack_one(const void* __restrict__ src,
                                                  u16* __restrict__ dst,
                                                  int c, int N, int srcbf) {
  int n = c % N;
  int t2 = c / N;
  int q = t2 & 3, kb = t2 >> 2;
  int k0 = kb * 32 + q * 8;
  u16 w[8];
  if (srcbf) {
    const u16* s = (const u16*)src;
#pragma unroll
    for (int j = 0; j < 8; j++) w[j] = s[(size_t)(k0 + j) * N + n];
  } else {
    const float* s = (const float*)src;
#pragma unroll
    for (int j = 0; j < 8; j++) w[j] = f2bf(s[(size_t)(k0 + j) * N + n]);
  }
  uint4 out;
  out.x = (unsigned)w[0] | ((unsigned)w[1] << 16);
  out.y = (unsigned)w[2] | ((unsigned)w[3] << 16);
  out.z = (unsigned)w[4] | ((unsigned)w[5] << 16);
  out.w = (unsigned)w[6] | ((unsigned)w[7] << 16);
  *((uint4*)(dst + (size_t)c * 8)) = out;
}

// ---------------- fused setup (1024 threads/block) ----------------
// bid 0      : CSR (verbatim) + zero sums + pre-convert att/bias params -> pconv
// bid 1..39  : repack W1p/W2p/Woutp
// bid 40..295: lin0 (4 nodes/block)
__global__ __launch_bounds__(1024) void setup_kernel(
    const unsigned* __restrict__ xdet,
    const void* __restrict__ xin,
    const int* __restrict__ ei,
    const void* __restrict__ Wl0, const void* __restrict__ Wr0,
    const void* __restrict__ W1, const void* __restrict__ W2, const void* __restrict__ Wout,
    const void* __restrict__ att0, const void* __restrict__ b0v,
    const void* __restrict__ att1, const void* __restrict__ b1v,
    int* __restrict__ csr_off, int* __restrict__ csr_src,
    float* __restrict__ sums, float* __restrict__ pconv,
    u16* __restrict__ W1p, u16* __restrict__ W2p, u16* __restrict__ Woutp,
    u16* __restrict__ xlb, u16* __restrict__ xrb) {
  int bid = blockIdx.x;
  int t = threadIdx.x;
  if (bid == 0) {
    int flagB = detect_flag(xdet);  // hoisted: ballot must run with full waves
    // ---- verbatim original build_csr_kernel body ----
    __shared__ int cnt[kN];
    __shared__ int tmp[kN];
    __shared__ int cur[kN];
    cnt[t] = 0;
    __syncthreads();
    for (int e = t; e < kE; e += 1024) atomicAdd(&cnt[ei[kE + e]], 1);
    __syncthreads();
    int deg = cnt[t] + 1;  // +1 self loop
    tmp[t] = deg;
    __syncthreads();
    for (int o = 1; o < kN; o <<= 1) {
      int add = (t >= o) ? tmp[t - o] : 0;
      __syncthreads();
      tmp[t] += add;
      __syncthreads();
    }
    int excl = tmp[t] - deg;
    csr_off[t] = excl;
    cur[t] = excl;
    if (t == kN - 1) csr_off[kN] = tmp[t];
    __syncthreads();
    for (int e = t; e < kE; e += 1024) {
      int s = ei[e], d2 = ei[kE + e];
      int pos = atomicAdd(&cur[d2], 1);
      csr_src[pos] = s;
    }
    int pos = atomicAdd(&cur[t], 1);  // self loop
    csr_src[pos] = t;
    if (t < 640) sums[t] = 0.f;  // zero sums0+sums1
    // pconv layout: [0:20) att0, [20:40) b0, [40:60) att1, [60:80) b1
    if (t >= 768 && t < 768 + 80) {
      int i = t - 768;
      const void* src = (i < 20) ? att0 : (i < 40) ? b0v : (i < 60) ? att1 : b1v;
      pconv[i] = ldconv(src, i % 20, flagB);
    }
  } else if (bid <= 39) {
    int flag = detect_flag(xdet);
    int c = (bid - 1) * 1024 + t;  // 0..39935
    if (c < 34816) repack_one(W1, W1p, c, 256, flag);               // K=1088,N=256
    else if (c < 38912) repack_one(W2, W2p, c - 34816, 128, flag);  // K=256, N=128
    else repack_one(Wout, Woutp, c - 38912, 64, flag);              // K=128, N=64
  } else {
    // lin0: x[b][n][0..7] @ Wl0/Wr0 -> xlb,xrb [n][b][20] bf16
    int flag = detect_flag(xdet);
    __shared__ __align__(16) float wl[8 * kHD], wr[8 * kHD];
    if (t < 8 * kHD) { wl[t] = ldconv(Wl0, t, flag); wr[t] = ldconv(Wr0, t, flag); }
    __syncthreads();
    int n = (bid - 40) * 4 + (t >> 8), b = t & 255;
    float xi[8];
    if (flag) {
      uint4 r = *((const uint4*)((const u16*)xin + ((size_t)b * kN + n) * 8));
      unpack2(r.x, xi[0], xi[1]); unpack2(r.y, xi[2], xi[3]);
      unpack2(r.z, xi[4], xi[5]); unpack2(r.w, xi[6], xi[7]);
    } else {
      const float4* s = (const float4*)((const float*)xin + ((size_t)b * kN + n) * 8);
      float4 v0 = s[0], v1 = s[1];
      xi[0] = v0.x; xi[1] = v0.y; xi[2] = v0.z; xi[3] = v0.w;
      xi[4] = v1.x; xi[5] = v1.y; xi[6] = v1.z; xi[7] = v1.w;
    }
    float ol[kHD], orr[kHD];
#pragma unroll
    for (int j = 0; j < kHD; j++) { ol[j] = 0.f; orr[j] = 0.f; }
#pragma unroll
    for (int i = 0; i < 8; i++) {
      float xv = xi[i];
#pragma unroll
      for (int j4 = 0; j4 < 5; j4++) {
        float4 wv = *((const float4*)&wl[i * kHD + j4 * 4]);
        float4 wu = *((const float4*)&wr[i * kHD + j4 * 4]);
        ol[j4 * 4 + 0] = fmaf(xv, wv.x, ol[j4 * 4 + 0]);
        ol[j4 * 4 + 1] = fmaf(xv, wv.y, ol[j4 * 4 + 1]);
        ol[j4 * 4 + 2] = fmaf(xv, wv.z, ol[j4 * 4 + 2]);
        ol[j4 * 4 + 3] = fmaf(xv, wv.w, ol[j4 * 4 + 3]);
        orr[j4 * 4 + 0] = fmaf(xv, wu.x, orr[j4 * 4 + 0]);
        orr[j4 * 4 + 1] = fmaf(xv, wu.y, orr[j4 * 4 + 1]);
        orr[j4 * 4 + 2] = fmaf(xv, wu.z, orr[j4 * 4 + 2]);
        orr[j4 * 4 + 3] = fmaf(xv, wu.w, orr[j4 * 4 + 3]);
      }
    }
    uint2* pl = (uint2*)(xlb + ((size_t)n * kB + b) * kHD);
    uint2* pr = (uint2*)(xrb + ((size_t)n * kB + b) * kHD);
#pragma unroll
    for (int k = 0; k < 5; k++) {
      pl[k] = make_uint2(pack_bf16(ol[4 * k], ol[4 * k + 1]), pack_bf16(ol[4 * k + 2], ol[4 * k + 3]));
      pr[k] = make_uint2(pack_bf16(orr[4 * k], orr[4 * k + 1]), pack_bf16(orr[4 * k + 2], orr[4 * k + 3]));
    }
  }
}

// ---------------- GATv2 attention (R3/R6 body; params pre-converted) -----------
__global__ __launch_bounds__(128) void attn_kernel(const u16* __restrict__ xlb,
                                                   const u16* __restrict__ xrb,
                                                   const int* __restrict__ csr_off,
                                                   const int* __restrict__ csr_src,
                                                   const float* __restrict__ attf,
                                                   const float* __restrict__ bf,
                                                   u16* __restrict__ hout,
                                                   float* __restrict__ sums) {
  __shared__ float satt[kHD], sbias[kHD];
  __shared__ float red[2][2 * kHD];
  int t = threadIdx.x;
  if (t < kHD) { satt[t] = attf[t]; sbias[t] = bf[t]; }
  __syncthreads();
  int bid = blockIdx.x;
  int h = ((bid & 7) >= 4) ? 1 : 0;
  int n = ((bid >> 3) << 2) | (bid & 3);
  int b = (h << 7) | t;

  float ratt[kHD];
#pragma unroll
  for (int f = 0; f < kHD; f++) ratt[f] = satt[f];

  float xrv[kHD];
  {
    const uint2* p = (const uint2*)(xrb + ((size_t)n * kB + b) * kHD);
#pragma unroll
    for (int k = 0; k < 5; k++) {
      uint2 v = p[k];
      unpack2(v.x, xrv[4 * k], xrv[4 * k + 1]);
      unpack2(v.y, xrv[4 * k + 2], xrv[4 * k + 3]);
    }
  }
  float s[4] = {0.f, 0.f, 0.f, 0.f};
  float acc[kHD];
#pragma unroll
  for (int f = 0; f < kHD; f++) acc[f] = 0.f;

  int beg = csr_off[n], end = csr_off[n + 1];
  uint2 r[5];
  {
    const uint2* p = (const uint2*)(xlb + ((size_t)csr_src[beg] * kB + b) * kHD);
#pragma unroll
    for (int k = 0; k < 5; k++) r[k] = p[k];
  }
  for (int idx = beg; idx < end; idx++) {
    float xs[kHD];
#pragma unroll
    for (int k = 0; k < 5; k++) {
      unpack2(r[k].x, xs[4 * k], xs[4 * k + 1]);
      unpack2(r[k].y, xs[4 * k + 2], xs[4 * k + 3]);
    }
    if (idx + 1 < end) {
      const uint2* p = (const uint2*)(xlb + ((size_t)csr_src[idx + 1] * kB + b) * kHD);
#pragma unroll
      for (int k = 0; k < 5; k++) r[k] = p[k];
    }
#pragma unroll
    for (int hh = 0; hh < 4; hh++) {
      float e = 0.f;
#pragma unroll
      for (int d = 0; d < 5; d++) {
        int f = hh * 5 + d;
        float v = xs[f] + xrv[f];
        v = fmaxf(v, 0.2f * v);
        e = fmaf(v, ratt[f], e);
      }
      float p = __expf(e);
      s[hh] += p;
#pragma unroll
      for (int d = 0; d < 5; d++) {
        int f = hh * 5 + d;
        acc[f] = fmaf(p, xs[f], acc[f]);
      }
    }
  }
  float hv[kHD];
#pragma unroll
  for (int hh = 0; hh < 4; hh++) {
    float inv = 1.f / s[hh];
#pragma unroll
    for (int d = 0; d < 5; d++) {
      int f = hh * 5 + d;
      hv[f] = fmaf(acc[f], inv, sbias[f]);
    }
  }
  {
    uint2* ph = (uint2*)(hout + ((size_t)n * kB + b) * kHD);
#pragma unroll
    for (int k = 0; k < 5; k++)
      ph[k] = make_uint2(pack_bf16(hv[4 * k], hv[4 * k + 1]), pack_bf16(hv[4 * k + 2], hv[4 * k + 3]));
  }
  int lane = t & 63, wv = t >> 6;
#pragma unroll
  for (int f = 0; f < kHD; f++) {
    float a = hv[f], q = hv[f] * hv[f];
    for (int o = 32; o > 0; o >>= 1) { a += __shfl_down(a, o); q += __shfl_down(q, o); }
    if (lane == 0) { red[wv][f] = a; red[wv][kHD + f] = q; }
  }
  __syncthreads();
  if (t < 2 * kHD) atomicAdd(&sums[(bid & 7) * 2 * kHD + t], red[0][t] + red[1][t]);
}

// ---------------- lin1 MFMA with inline BN0 fold (fold1 fused per-block) -------
__global__ __launch_bounds__(256) void lin1_mfma_kernel(const u16* __restrict__ hb,
                                                        const float* __restrict__ sums0,
                                                        const void* __restrict__ g0,
                                                        const void* __restrict__ be0,
                                                        const void* __restrict__ Wl1,
                                                        const void* __restrict__ Wr1,
                                                        const unsigned* __restrict__ xdet,
                                                        u16* __restrict__ xlb,
                                                        u16* __restrict__ xrb) {
  __shared__ float sa[kHD], sc[kHD], tot[2 * kHD], b48[48];
  int flag = detect_flag(xdet);
  int t = threadIdx.x;
  if (t < 2 * kHD) {
    float v = 0.f;
    for (int k = 0; k < 8; k++) v += sums0[k * 2 * kHD + t];
    tot[t] = v;
  }
  __syncthreads();
  if (t < kHD) {
    const float inv = 1.0f / (float)(kN * kB);
    float mu = tot[t] * inv;
    float var = tot[kHD + t] * inv - mu * mu;
    float av = ldconv(g0, t, flag) * rsqrtf(var + kEps);
    sa[t] = av;
    sc[t] = ldconv(be0, t, flag) - mu * av;
  }
  __syncthreads();
  if (t < 48) {
    float bv = 0.f;
    if (t < 20) {
      for (int f = 0; f < kHD; f++) bv += sc[f] * ldconv(Wl1, f * kHD + t, flag);
    } else if (t < 40) {
      for (int f = 0; f < kHD; f++) bv += sc[f] * ldconv(Wr1, f * kHD + (t - 20), flag);
    }
    b48[t] = bv;
  }
  __syncthreads();
  int wave = t >> 6, lane = t & 63;
  int lo = lane & 15, quad = lane >> 4;
  // per-lane B-fragments built directly from global weights (L2-broadcast reads)
  short8 bfr0, bfr1, bfr2;
  float bc0, bc1, bc2;
  {
    u16 w[3][8];
#pragma unroll
    for (int c3 = 0; c3 < 3; c3++) {
      int ncol = c3 * 16 + lo;
#pragma unroll
      for (int jj = 0; jj < 8; jj++) {
        int k = quad * 8 + jj;
        float val = 0.f;
        if (k < kHD && ncol < 40) {
          float raw = (ncol < kHD) ? ldconv(Wl1, k * kHD + ncol, flag)
                                   : ldconv(Wr1, k * kHD + (ncol - 20), flag);
          val = sa[k] * raw;
        }
        w[c3][jj] = f2bf(val);
      }
    }
    union { unsigned u[4]; short8 s; } cv;
#define PACK_FRAG(dst, arr) \
    cv.u[0] = (unsigned)arr[0] | ((unsigned)arr[1] << 16); \
    cv.u[1] = (unsigned)arr[2] | ((unsigned)arr[3] << 16); \
    cv.u[2] = (unsigned)arr[4] | ((unsigned)arr[5] << 16); \
    cv.u[3] = (unsigned)arr[6] | ((unsigned)arr[7] << 16); \
    dst = cv.s;
    PACK_FRAG(bfr0, w[0]) PACK_FRAG(bfr1, w[1]) PACK_FRAG(bfr2, w[2])
#undef PACK_FRAG
    bc0 = b48[lo]; bc1 = b48[16 + lo]; bc2 = b48[32 + lo];
  }
  int wtile0 = (blockIdx.x * 4 + wave) * 8;
  for (int it = 0; it < 8; it++) {
    int m0 = (wtile0 + it) << 4;
    const uint2* p = (const uint2*)(hb + (size_t)(m0 + lo) * kHD);
    uint2 w0 = p[0], w1 = p[1], w2 = p[2], w3 = p[3], w4 = p[4];
    unsigned aw0 = quad == 0 ? w0.x : quad == 1 ? w2.x : quad == 2 ? w4.x : 0u;
    unsigned aw1 = quad == 0 ? w0.y : quad == 1 ? w2.y : quad == 2 ? w4.y : 0u;
    unsigned aw2 = quad == 0 ? w1.x : quad == 1 ? w3.x : 0u;
    unsigned aw3 = quad == 0 ? w1.y : quad == 1 ? w3.y : 0u;
    union { unsigned u[4]; short8 s; } cvt;
    cvt.u[0] = aw0; cvt.u[1] = aw1; cvt.u[2] = aw2; cvt.u[3] = aw3;
    short8 a = cvt.s;
    floatx4 acc0 = {0.f, 0.f, 0.f, 0.f};
    floatx4 acc1 = {0.f, 0.f, 0.f, 0.f};
    floatx4 acc2 = {0.f, 0.f, 0.f, 0.f};
    acc0 = __builtin_amdgcn_mfma_f32_16x16x32_bf16(a, bfr0, acc0, 0, 0, 0);
    acc1 = __builtin_amdgcn_mfma_f32_16x16x32_bf16(a, bfr1, acc1, 0, 0, 0);
    acc2 = __builtin_amdgcn_mfma_f32_16x16x32_bf16(a, bfr2, acc2, 0, 0, 0);
#pragma unroll
    for (int r = 0; r < 4; r++) {
      size_t row = (size_t)(m0 + quad * 4 + r);
      xlb[row * kHD + lo] = f2bf(acc0[r] + bc0);          // cols 0-15
      int c1 = 16 + lo;                                    // cols 16-31
      float v1 = acc1[r] + bc1;
      if (c1 < kHD) xlb[row * kHD + c1] = f2bf(v1);
      else xrb[row * kHD + (c1 - kHD)] = f2bf(v1);
      int c2 = 12 + lo;                                    // cols 32-47 -> xrb 12-19
      if (c2 < kHD) xrb[row * kHD + c2] = f2bf(acc2[r] + bc2);
    }
  }
}

// ---------------- pool + BN1 + agg + obs -> FIN[256,1088] bf16 ----------------
__global__ __launch_bounds__(256) void pool_fin_kernel(const u16* __restrict__ hb,
                                                       const float* __restrict__ sums1,
                                                       const void* __restrict__ g1,
                                                       const void* __restrict__ be1,
                                                       const void* __restrict__ Wagg,
                                                       const void* __restrict__ bagg,
                                                       const void* __restrict__ obsraw,
                                                       const unsigned* __restrict__ xdet,
                                                       u16* __restrict__ finb) {
  int flag = detect_flag(xdet);
  int b = blockIdx.x, t = threadIdx.x;
  float acc[kHD];
#pragma unroll
  for (int f = 0; f < kHD; f++) acc[f] = 0.f;
  for (int n = t; n < kN; n += 256) {
    const uint2* p = (const uint2*)(hb + ((size_t)n * kB + b) * kHD);
#pragma unroll
    for (int k = 0; k < 5; k++) {
      uint2 v = p[k];
      float a0, a1, a2, a3;
      unpack2(v.x, a0, a1); unpack2(v.y, a2, a3);
      acc[4 * k] += a0; acc[4 * k + 1] += a1; acc[4 * k + 2] += a2; acc[4 * k + 3] += a3;
    }
  }
  __shared__ float red[4][kHD];
  __shared__ float tot[2 * kHD], pv[kHD];
#pragma unroll
  for (int f = 0; f < kHD; f++) {
    float v = acc[f];
    for (int o = 32; o > 0; o >>= 1) v += __shfl_down(v, o);
    if ((t & 63) == 0) red[t >> 6][f] = v;
  }
  if (t < 2 * kHD) {
    float v = 0.f;
    for (int k = 0; k < 8; k++) v += sums1[k * 2 * kHD + t];
    tot[t] = v;
  }
  __syncthreads();
  if (t < kHD) {
    const float inv = 1.0f / (float)(kN * kB);
    float mu = tot[t] * inv;
    float var = tot[kHD + t] * inv - mu * mu;
    float a1 = ldconv(g1, t, flag) * rsqrtf(var + kEps);
    float c1 = ldconv(be1, t, flag) - mu * a1;
    float pool = (red[0][t] + red[1][t] + red[2][t] + red[3][t]) * (1.0f / kN);
    pv[t] = pool * a1 + c1;
  }
  __syncthreads();
  if (t < 64) {
    float agg = ldconv(bagg, t, flag);
#pragma unroll
    for (int f = 0; f < kHD; f++) agg = fmaf(pv[f], ldconv(Wagg, f * 64 + t, flag), agg);
    finb[(size_t)b * 1088 + t] = f2bf(agg);
  }
  if (t < 128) {
    uint4* dst = (uint4*)(finb + (size_t)b * 1088 + 64 + t * 8);
    if (flag) {
      *dst = *((const uint4*)((const u16*)obsraw + (size_t)b * 1024 + t * 8));
    } else {
      const float4* s = (const float4*)((const float*)obsraw + (size_t)b * 1024 + t * 8);
      float4 r0 = s[0], r1 = s[1];
      uint4 o;
      o.x = pack_bf16(r0.x, r0.y); o.y = pack_bf16(r0.z, r0.w);
      o.z = pack_bf16(r1.x, r1.y); o.w = pack_bf16(r1.z, r1.w);
      *dst = o;
    }
  }
}

// ---------------- MLP layer 1 via MFMA (known-good) ----------------
__global__ __launch_bounds__(256) void mlp1_kernel(const u16* __restrict__ finb,
                                                   const u16* __restrict__ W1p,
                                                   const void* __restrict__ bh1,
                                                   const unsigned* __restrict__ xdet,
                                                   u16* __restrict__ h1b) {
  int flag = detect_flag(xdet);
  int tid = threadIdx.x;
  int wave = tid >> 6, lane = tid & 63;
  int tile = blockIdx.x * 4 + wave;            // 0..255
  int m0 = (tile >> 4) << 4, n0 = (tile & 15) << 4;
  int lo = lane & 15, quad = lane >> 4;
  floatx4 acc = {0.f, 0.f, 0.f, 0.f};
  const u16* ap = finb + (size_t)(m0 + lo) * 1088 + quad * 8;
  const u16* bp = W1p + ((size_t)quad * 256 + n0 + lo) * 8;
  for (int kb = 0; kb < 34; kb++) {
    short8 a = *(const short8*)ap; ap += 32;
    short8 bfr = *(const short8*)bp; bp += 4 * 256 * 8;
    acc = __builtin_amdgcn_mfma_f32_16x16x32_bf16(a, bfr, acc, 0, 0, 0);
  }
  float bias = ldconv(bh1, n0 + lo, flag);
  u16* op = h1b + (size_t)(m0 + quad * 4) * 256 + n0 + lo;
#pragma unroll
  for (int r = 0; r < 4; r++) op[r * 256] = f2bf(tanhf(acc[r] + bias));
}

// ---------------- MLP layers 2+3 via MFMA -> logits (known-good) ----
__global__ __launch_bounds__(256) void mlp23_kernel(const u16* __restrict__ h1b,
                                                    const u16* __restrict__ W2p,
                                                    const u16* __restrict__ Woutp,
                                                    const void* __restrict__ bh2,
                                                    const void* __restrict__ bout,
                                                    const unsigned* __restrict__ xdet,
                                                    void* __restrict__ outv) {
  __shared__ __align__(16) u16 h2s[16][128];
  int flag = detect_flag(xdet);
  int tid = threadIdx.x;
  int wave = tid >> 6, lane = tid & 63;
  int lo = lane & 15, quad = lane >> 4;
  int m0 = blockIdx.x * 16;
#pragma unroll
  for (int i = 0; i < 2; i++) {
    int n0 = (wave * 2 + i) * 16;
    floatx4 acc = {0.f, 0.f, 0.f, 0.f};
    const u16* ap = h1b + (size_t)(m0 + lo) * 256 + quad * 8;
    const u16* bp = W2p + ((size_t)quad * 128 + n0 + lo) * 8;
    for (int kb = 0; kb < 8; kb++) {
      short8 a = *(const short8*)ap; ap += 32;
      short8 bfr = *(const short8*)bp; bp += 4 * 128 * 8;
      acc = __builtin_amdgcn_mfma_f32_16x16x32_bf16(a, bfr, acc, 0, 0, 0);
    }
    float bias = ldconv(bh2, n0 + lo, flag);
#pragma unroll
    for (int r = 0; r < 4; r++) h2s[quad * 4 + r][n0 + lo] = f2bf(tanhf(acc[r] + bias));
  }
  __syncthreads();
  {
    int n0 = wave * 16;
    floatx4 acc = {0.f, 0.f, 0.f, 0.f};
    const u16* bp = Woutp + ((size_t)quad * 64 + n0 + lo) * 8;
    for (int kb = 0; kb < 4; kb++) {
      short8 a = *(const short8*)(&h2s[lo][kb * 32 + quad * 8]);
      short8 bfr = *(const short8*)bp; bp += 4 * 64 * 8;
      acc = __builtin_amdgcn_mfma_f32_16x16x32_bf16(a, bfr, acc, 0, 0, 0);
    }
    float bias = ldconv(bout, n0 + lo, flag);
    if (flag) {
      __hip_bfloat16* o = (__hip_bfloat16*)outv;
#pragma unroll
      for (int r = 0; r < 4; r++)
        o[(size_t)(m0 + quad * 4 + r) * 64 + n0 + lo] = __float2bfloat16(acc[r] + bias);
    } else {
      float* o = (float*)outv;
#pragma unroll
      for (int r = 0; r < 4; r++)
        o[(size_t)(m0 + quad * 4 + r) * 64 + n0 + lo] = acc[r] + bias;
    }
  }
}

// ---------------- launch: 7 dispatches, no memset ----------------
extern "C" void kernel_launch(void* const* d_in, const int* in_sizes, int n_in,
                              void* d_out, int out_size, void* d_ws, size_t ws_size,
                              hipStream_t stream) {
  char* ws = (char*)d_ws;
  float* sums    = (float*)(ws + 0);         // 640 floats: sums0[320]+sums1[320]
  float* sums0   = sums;
  float* sums1   = sums + 320;
  int*   csr_off = (int*)(ws + 2560);        // 4100 B
  int*   csr_src = (int*)(ws + 6912);        // 36864 B -> 43776
  u16*   W1p     = (u16*)(ws + 44032);       // 557056 -> 601088
  u16*   W2p     = (u16*)(ws + 601088);      // 65536  -> 666624
  u16*   Woutp   = (u16*)(ws + 666624);      // 16384  -> 683008
  u16*   h1b     = (u16*)(ws + 683008);      // 131072 -> 814080
  u16*   finb    = (u16*)(ws + 814080);      // 557056 -> 1371136
  float* pconv   = (float*)(ws + 1371136);   // 320 B  -> 1371456
  u16*   xlb     = (u16*)(ws + 1374720);     // 10485760 -> 11860480
  u16*   xrb     = (u16*)(ws + 11860480);    // 10485760 -> 22346240
  u16*   hb      = (u16*)(ws + 22346240);    // 10485760 -> 32832000

  const unsigned* xdet = (const unsigned*)d_in[0];
  const int* ei = (const int*)d_in[2];

  setup_kernel<<<296, 1024, 0, stream>>>(xdet, d_in[0], ei,
                                         d_in[3], d_in[4],              // Wl0, Wr0
                                         d_in[17], d_in[19], d_in[21],  // W1, W2, Wout
                                         d_in[5], d_in[6],              // att0, b0
                                         d_in[9], d_in[10],             // att1, b1
                                         csr_off, csr_src, sums, pconv,
                                         W1p, W2p, Woutp, xlb, xrb);
  attn_kernel<<<2 * kN, 128, 0, stream>>>(xlb, xrb, csr_off, csr_src,
                                          pconv, pconv + 20, hb, sums0);
  lin1_mfma_kernel<<<512, 256, 0, stream>>>(hb, sums0, d_in[11], d_in[12],
                                            d_in[7], d_in[8], xdet, xlb, xrb);
  attn_kernel<<<2 * kN, 128, 0, stream>>>(xlb, xrb, csr_off, csr_src,
                                          pconv + 40, pconv + 60, hb, sums1);
  pool_fin_kernel<<<kB, 256, 0, stream>>>(hb, sums1, d_in[13], d_in[14],
                                          d_in[15], d_in[16], d_in[1], xdet, finb);
  mlp1_kernel<<<64, 256, 0, stream>>>(finb, W1p, d_in[18], xdet, h1b);
  mlp23_kernel<<<16, 256, 0, stream>>>(h1b, W2p, Woutp, d_in[20], d_in[22], xdet, d_out);
}